// Round 10
// baseline (5507.907 us; speedup 1.0000x reference)
//
#include <hip/hip_runtime.h>
#include <cmath>

namespace {

typedef _Float16 f16;
typedef f16 f16x8 __attribute__((ext_vector_type(8)));
typedef f16 f16x4 __attribute__((ext_vector_type(4)));
typedef float f32x4 __attribute__((ext_vector_type(4)));

constexpr int B  = 4096;
constexpr int H  = 1024;
constexpr int FH = 4 * H;   // 4096
constexpr int NSTEPS = 45;
constexpr float INVS = 1.0f / 2048.0f;

__device__ __forceinline__ float sigf(float x) { return 1.0f / (1.0f + expf(-x)); }

struct HL { f16 h, l; };
// safe split: hi is 0 or a normal f16; lo = f16((a-hi)*2048) (normal or negligible)
__device__ __forceinline__ HL split16(float a) {
  float ah = (float)(f16)a;
  if (fabsf(a) < 6.1035156e-5f) ah = 0.0f;   // would-be-subnormal hi -> push all into lo
  HL r; r.h = (f16)ah; r.l = (f16)((a - ah) * 2048.0f); return r;
}

__device__ __forceinline__ void async16(f16* lds_dst, const f16* gsrc) {
  __builtin_amdgcn_global_load_lds(
      (const __attribute__((address_space(1))) void*)gsrc,
      (__attribute__((address_space(3))) void*)lds_dst, 16, 0, 0);
}

// ---------------- one-time: split W_hh into f16 hi/lo ----------------
__global__ void convertW_kernel(const float* __restrict__ W,
                                f16* __restrict__ Whi, f16* __restrict__ Wlo) {
  size_t i = ((size_t)blockIdx.x * 256 + threadIdx.x) * 4;
  float4 v = *(const float4*)(W + i);
  HL a = split16(v.x), b = split16(v.y), c = split16(v.z), d = split16(v.w);
  f16x4 hi = {a.h, b.h, c.h, d.h};
  f16x4 lo = {a.l, b.l, c.l, d.l};
  *(f16x4*)(Whi + i) = hi;
  *(f16x4*)(Wlo + i) = lo;
}

// ---------------- one-time precompute of x-path tables (wave-parallel) ----------------
__global__ void precompute_kernel(
    const float* __restrict__ W_ih, const float* __restrict__ b_ih, const float* __restrict__ b_hh,
    const float* __restrict__ depth_emb, const float* __restrict__ ratio_emb, const float* __restrict__ ks_emb,
    const float* __restrict__ cond_emb, const float* __restrict__ sc_emb, const int* __restrict__ sid_p,
    float* __restrict__ tblD, float* __restrict__ tblR, float* __restrict__ tblK,
    float* __restrict__ condp, float* __restrict__ base0) {
  const int w4   = threadIdx.x >> 6;
  const int lane = threadIdx.x & 63;
  const int j    = blockIdx.x * 4 + w4;
  const float* wr = W_ih + (size_t)j * H;
  const int k = lane * 16;
  float4 wv0 = *(const float4*)(wr + k);
  float4 wv1 = *(const float4*)(wr + k + 4);
  float4 wv2 = *(const float4*)(wr + k + 8);
  float4 wv3 = *(const float4*)(wr + k + 12);

  auto dot = [&](const float* e) -> float {
    float4 e0 = *(const float4*)(e);
    float4 e1 = *(const float4*)(e + 4);
    float4 e2 = *(const float4*)(e + 8);
    float4 e3 = *(const float4*)(e + 12);
    return e0.x*wv0.x + e0.y*wv0.y + e0.z*wv0.z + e0.w*wv0.w
         + e1.x*wv1.x + e1.y*wv1.y + e1.z*wv1.z + e1.w*wv1.w
         + e2.x*wv2.x + e2.y*wv2.y + e2.z*wv2.z + e2.w*wv2.w
         + e3.x*wv3.x + e3.y*wv3.y + e3.z*wv3.z + e3.w*wv3.w;
  };

  float a[15];
  a[0] = dot(depth_emb + k);       a[1] = dot(depth_emb + H + k);   a[2] = dot(depth_emb + 2*H + k);
  a[3] = dot(ratio_emb + k);       a[4] = dot(ratio_emb + H + k);   a[5] = dot(ratio_emb + 2*H + k);
  a[6] = dot(ks_emb + k);          a[7] = dot(ks_emb + H + k);      a[8] = dot(ks_emb + 2*H + k);
  a[9] = a[10] = a[11] = a[12] = a[13] = a[14] = 0.0f;
  constexpr int HH = H / 2;
  int sid = sid_p[0];
  if (lane < 32) {
    a[9]  = dot(cond_emb + 0*HH + k);
    a[10] = dot(cond_emb + 1*HH + k);
    a[11] = dot(cond_emb + 2*HH + k);
    a[12] = dot(cond_emb + 3*HH + k);
    a[13] = dot(cond_emb + 4*HH + k);
  } else {
    a[14] = dot(sc_emb + sid*HH + (k - HH));   // pairs with wr[HH + kk]
  }
  #pragma unroll
  for (int i = 0; i < 15; ++i) {
    #pragma unroll
    for (int off = 32; off > 0; off >>= 1) a[i] += __shfl_xor(a[i], off);
  }
  if (lane == 0) {
    float bias = b_ih[j] + b_hh[j];
    tblD[0*FH+j]=a[0]+bias; tblD[1*FH+j]=a[1]+bias; tblD[2*FH+j]=a[2]+bias;
    tblR[0*FH+j]=a[3]+bias; tblR[1*FH+j]=a[4]+bias; tblR[2*FH+j]=a[5]+bias;
    tblK[0*FH+j]=a[6]+bias; tblK[1*FH+j]=a[7]+bias; tblK[2*FH+j]=a[8]+bias;
    condp[0*FH+j]=a[9]; condp[1*FH+j]=a[10]; condp[2*FH+j]=a[11];
    condp[3*FH+j]=a[12]; condp[4*FH+j]=a[13];
    base0[j] = a[14] + bias;
  }
}

// ---------------- step 0: h=c=0 ----------------
__global__ void step0_kernel(const float* __restrict__ constraints,
                             const float* __restrict__ condp, const float* __restrict__ base0,
                             f16* __restrict__ hhi, f16* __restrict__ hlo, float* __restrict__ c) {
  int idx = blockIdx.x * blockDim.x + threadIdx.x;   // b*H + j
  int b = idx >> 10;
  int j = idx & (H - 1);
  float cv = constraints[b];
  int i0 = 0;
  if (cv >= 12.5f) i0 = 1;
  if (cv >= 15.0f) i0 = 2;
  if (cv >= 17.5f) i0 = 3;
  float right = 10.0f + 2.5f * (float)(i0 + 1);
  float w = (right - cv) / 2.5f;
  const float* c0 = condp + (size_t)i0 * FH;
  const float* c1 = c0 + FH;
  float iw = 1.0f - w;
  float xi = w*c0[j]       + iw*c1[j]       + base0[j];
  float xg = w*c0[2*H+j]   + iw*c1[2*H+j]   + base0[2*H+j];
  float xo = w*c0[3*H+j]   + iw*c1[3*H+j]   + base0[3*H+j];
  float cn = sigf(xi) * tanhf(xg);
  float hn = sigf(xo) * tanhf(cn);
  c[idx] = cn;
  HL s = split16(hn);
  hhi[idx] = s.h; hlo[idx] = s.l;
}

// ---------------- MFMA LSTM step: 256x128 tile, 8 waves, 4-phase m201-style ----------
// LDS buffer (f16 elems): AH[0,8192) AL[8192,16384) BH[16384,20480) BL[20480,24576)
// Rows [row][32 k], 16B-chunk swizzle: phys = kq ^ (R&3) ^ ((R>>2)&3).
// Per K-tile: 4 phases (one per gate nf). Phase = {reads + 2 stage-issues ->
// s_barrier -> lgkmcnt(0) [no sched_barrier: m141] -> setprio(1) 12 MFMA
// setprio(0) -> s_barrier}. One counted vmcnt(6) per tile at P3 (full-tile
// issue distance); 3-buffer rotation, stage kt+2 during kt (R5 safety proof).
constexpr int BUFE = 24576;   // 48 KB per buffer

__global__ __launch_bounds__(512, 2) void lstm_step_mfma(
    const f16* __restrict__ hhi, const f16* __restrict__ hlo,
    f16* __restrict__ nhhi, f16* __restrict__ nhlo,
    float* __restrict__ cbuf,
    const f16* __restrict__ Whi, const f16* __restrict__ Wlo,
    const float* __restrict__ tbl, const int* __restrict__ sel) {
  __shared__ __align__(16) f16 lds[3 * BUFE];   // 144 KB

  const int tid  = threadIdx.x;
  const int lane = tid & 63;
  const int w    = tid >> 6;
  const int wm   = w >> 1, wn = w & 1;
  const int l15  = lane & 15;
  const int kq   = lane >> 4;

  // XCD-clustered tile assignment (per-XCD W slice stays in its private L2)
  const int L   = blockIdx.x;          // 0..511
  const int xcd = L & 7, seq = L >> 3;
  const int jb  = (xcd << 2) + (seq & 3);
  const int bb  = seq >> 2;
  const int b0  = bb << 8;
  const int j0  = jb << 5;

  f32x4 accH[4][4] = {};
  f32x4 accL[4][4] = {};

  // ---- loop-invariant fragment offsets (f16 elems) ----
  int offA[4], offB[4];
  #pragma unroll
  for (int mf = 0; mf < 4; ++mf) {
    int R = wm * 64 + mf * 16 + l15;
    int c = kq ^ (R & 3) ^ ((R >> 2) & 3);
    offA[mf] = R * 32 + c * 8;
  }
  #pragma unroll
  for (int nf = 0; nf < 4; ++nf) {
    int R = nf * 32 + wn * 16 + l15;
    int c = kq ^ (R & 3) ^ ((R >> 2) & 3);
    offB[nf] = 16384 + R * 32 + c * 8;
  }

  // ---- loop-invariant staging addresses ----
  const int rs = tid >> 2, cs = tid & 3;
  const int r1 = 128 + rs;
  const int cl0 = cs ^ (rs & 3) ^ ((rs >> 2) & 3);
  const int cl1 = cs ^ (r1 & 3) ^ ((r1 >> 2) & 3);
  const int wrow = ((rs >> 5) << 10) + j0 + (rs & 31);   // gate-major permuted W row
  const f16* sA0h = hhi + (size_t)(b0 + rs) * H + cl0 * 8;
  const f16* sA0l = hlo + (size_t)(b0 + rs) * H + cl0 * 8;
  const f16* sA1h = hhi + (size_t)(b0 + r1) * H + cl1 * 8;
  const f16* sA1l = hlo + (size_t)(b0 + r1) * H + cl1 * 8;
  const f16* sBh  = Whi + (size_t)wrow * H + cl0 * 8;
  const f16* sBl  = Wlo + (size_t)wrow * H + cl0 * 8;
  const int dA0 = w * 512, dA1 = 4096 + w * 512, dB = 16384 + w * 512;

  auto stage6 = [&](f16* buf, int ko) {
    async16(buf + dA0,        sA0h + ko);
    async16(buf + dA0 + 8192, sA0l + ko);
    async16(buf + dA1,        sA1h + ko);
    async16(buf + dA1 + 8192, sA1l + ko);
    async16(buf + dB,         sBh + ko);
    async16(buf + dB + 4096,  sBl + ko);
  };

  f16 *bA = lds, *bB = lds + BUFE, *bC = lds + 2 * BUFE;

  // prologue: stage tiles 0,1; wait for tile 0 only (counted)
  stage6(bA, 0);
  stage6(bB, 32);
  asm volatile("s_waitcnt vmcnt(6)" ::: "memory");
  __builtin_amdgcn_s_barrier();

  for (int kt = 0; kt < 32; ++kt) {
    const int ko2 = (kt + 2) * 32;
    const bool pre = (kt < 30);
    f16x8 ah[4], al[4];

    #pragma unroll
    for (int nf = 0; nf < 4; ++nf) {
      // ---- phase reads ----
      if (nf == 0) {
        #pragma unroll
        for (int mf = 0; mf < 4; ++mf) ah[mf] = *(const f16x8*)(bA + offA[mf]);
        #pragma unroll
        for (int mf = 0; mf < 4; ++mf) al[mf] = *(const f16x8*)(bA + offA[mf] + 8192);
      }
      f16x8 bh = *(const f16x8*)(bA + offB[nf]);
      f16x8 bl = *(const f16x8*)(bA + offB[nf] + 4096);
      // ---- 2 stage issues per phase (P0-P2) for tile kt+2 ----
      if (pre) {
        if (nf == 0) { async16(bC + dA0, sA0h + ko2); async16(bC + dA0 + 8192, sA0l + ko2); }
        if (nf == 1) { async16(bC + dA1, sA1h + ko2); async16(bC + dA1 + 8192, sA1l + ko2); }
        if (nf == 2) { async16(bC + dB,  sBh + ko2);  async16(bC + dB + 4096,  sBl + ko2); }
      }
      __builtin_amdgcn_s_barrier();
      asm volatile("s_waitcnt lgkmcnt(0)" ::: "memory");
      __builtin_amdgcn_s_setprio(1);
      #pragma unroll
      for (int mf = 0; mf < 4; ++mf)
        accH[mf][nf] = __builtin_amdgcn_mfma_f32_16x16x32_f16(ah[mf], bh, accH[mf][nf], 0, 0, 0);
      #pragma unroll
      for (int mf = 0; mf < 4; ++mf)
        accL[mf][nf] = __builtin_amdgcn_mfma_f32_16x16x32_f16(ah[mf], bl, accL[mf][nf], 0, 0, 0);
      #pragma unroll
      for (int mf = 0; mf < 4; ++mf)
        accL[mf][nf] = __builtin_amdgcn_mfma_f32_16x16x32_f16(al[mf], bh, accL[mf][nf], 0, 0, 0);
      __builtin_amdgcn_s_setprio(0);
      if (nf == 3) {
        // end of tile: tile kt+1's 6 stage loads (issued last tile) must have
        // landed; tile kt+2's 6 (issued this tile) stay in flight.
        if (pre) asm volatile("s_waitcnt vmcnt(6)" ::: "memory");
        else     asm volatile("s_waitcnt vmcnt(0)" ::: "memory");
      }
      __builtin_amdgcn_s_barrier();
    }

    f16* t = bA; bA = bB; bB = bC; bC = t;
  }

  // epilogue: gates -> LSTM cell -> c, h(hi/lo)
  const int j = j0 + wn * 16 + l15;
  #pragma unroll
  for (int mf = 0; mf < 4; ++mf) {
    #pragma unroll
    for (int r = 0; r < 4; ++r) {
      int b = b0 + wm * 64 + mf * 16 + kq * 4 + r;
      int s = sel[b];
      const float* tb = tbl + (size_t)s * FH + j;
      float gi = accH[mf][0][r] + accL[mf][0][r] * INVS + tb[0];
      float gf = accH[mf][1][r] + accL[mf][1][r] * INVS + tb[H];
      float gg = accH[mf][2][r] + accL[mf][2][r] * INVS + tb[2*H];
      float go = accH[mf][3][r] + accL[mf][3][r] * INVS + tb[3*H];
      size_t off = (size_t)b * H + j;
      float cp = cbuf[off];
      float cn = sigf(gf) * cp + sigf(gi) * tanhf(gg);
      float hn = sigf(go) * tanhf(cn);
      cbuf[off] = cn;
      HL sp = split16(hn);
      nhhi[off] = sp.h;
      nhlo[off] = sp.l;
    }
  }
}

// ---------------- sampler ----------------
__global__ void sampler_kernel(const f16* __restrict__ hhi, const f16* __restrict__ hlo,
                               const float* __restrict__ selW, const float* __restrict__ selb,
                               const float* __restrict__ gu,
                               float* __restrict__ val_out, float* __restrict__ wb_out,
                               float* __restrict__ p_out,
                               float v0, float v1, float v2,
                               int* __restrict__ sel) {
  int wave = threadIdx.x >> 6;
  int lane = threadIdx.x & 63;
  int b = blockIdx.x * 4 + wave;
  const f16* hh = hhi + (size_t)b * H;
  const f16* hl = hlo + (size_t)b * H;
  float acc0 = 0, acc1 = 0, acc2 = 0;
  #pragma unroll
  for (int ch = 0; ch < 4; ++ch) {
    int k = ch * 256 + lane * 4;
    f16x4 vh = *(const f16x4*)(hh + k);
    f16x4 vl = *(const f16x4*)(hl + k);
    float x0 = (float)vh[0] + (float)vl[0] * INVS;
    float x1 = (float)vh[1] + (float)vl[1] * INVS;
    float x2 = (float)vh[2] + (float)vl[2] * INVS;
    float x3 = (float)vh[3] + (float)vl[3] * INVS;
    float4 w0 = *(const float4*)(selW + k);
    float4 w1 = *(const float4*)(selW + H + k);
    float4 w2 = *(const float4*)(selW + 2*H + k);
    acc0 += x0*w0.x + x1*w0.y + x2*w0.z + x3*w0.w;
    acc1 += x0*w1.x + x1*w1.y + x2*w1.z + x3*w1.w;
    acc2 += x0*w2.x + x1*w2.y + x2*w2.z + x3*w2.w;
  }
  #pragma unroll
  for (int off = 32; off > 0; off >>= 1) {
    acc0 += __shfl_xor(acc0, off);
    acc1 += __shfl_xor(acc1, off);
    acc2 += __shfl_xor(acc2, off);
  }
  if (lane == 0) {
    float y0 = acc0 + selb[0] - logf(-logf(gu[(size_t)b*3 + 0]));
    float y1 = acc1 + selb[1] - logf(-logf(gu[(size_t)b*3 + 1]));
    float y2 = acc2 + selb[2] - logf(-logf(gu[(size_t)b*3 + 2]));
    int s = 0;
    float best = y0;
    if (y1 > best) { s = 1; best = y1; }
    if (y2 > best) { s = 2; best = y2; }
    float e0 = expf(y0 - best), e1 = expf(y1 - best), e2 = expf(y2 - best);
    float inv = 1.0f / (e0 + e1 + e2);
    float p0 = e0 * inv, p1 = e1 * inv, p2 = e2 * inv;
    val_out[b] = (s == 0) ? v0 : ((s == 1) ? v1 : v2);
    wb_out[(size_t)b*3 + 0] = (s == 0) ? 1.0f : 0.0f;
    wb_out[(size_t)b*3 + 1] = (s == 1) ? 1.0f : 0.0f;
    wb_out[(size_t)b*3 + 2] = (s == 2) ? 1.0f : 0.0f;
    p_out[(size_t)b*3 + 0] = p0;
    p_out[(size_t)b*3 + 1] = p1;
    p_out[(size_t)b*3 + 2] = p2;
    sel[b] = s;
  }
}

}  // namespace

extern "C" void kernel_launch(void* const* d_in, const int* in_sizes, int n_in,
                              void* d_out, int out_size, void* d_ws, size_t ws_size,
                              hipStream_t stream) {
  (void)in_sizes; (void)n_in; (void)out_size; (void)ws_size;
  const float* constraints = (const float*)d_in[0];
  const int*   sid         = (const int*)d_in[1];
  const float* gumbel      = (const float*)d_in[2];
  const float* cond_emb    = (const float*)d_in[3];
  const float* sc_emb      = (const float*)d_in[4];
  const float* depth_emb   = (const float*)d_in[5];
  const float* ratio_emb   = (const float*)d_in[6];
  const float* ks_emb      = (const float*)d_in[7];
  const float* W_ih        = (const float*)d_in[8];
  const float* b_ih        = (const float*)d_in[9];
  const float* W_hh        = (const float*)d_in[10];
  const float* b_hh        = (const float*)d_in[11];
  const float* depth_W     = (const float*)d_in[12];
  const float* depth_b     = (const float*)d_in[13];
  const float* width_W     = (const float*)d_in[14];
  const float* width_b     = (const float*)d_in[15];
  const float* ks_W        = (const float*)d_in[16];
  const float* ks_b        = (const float*)d_in[17];

  float* out = (float*)d_out;
  float* ws  = (float*)d_ws;

  float* cb    = ws;                                 // B*H f32 (16MB)
  f16*   W16hi = (f16*)(cb + (size_t)B * H);         // FH*H f16 (8MB)
  f16*   W16lo = W16hi + (size_t)FH * H;             // 8MB
  f16*   hhiA  = W16lo + (size_t)FH * H;             // B*H f16
  f16*   hloA  = hhiA + (size_t)B * H;
  f16*   hhiB  = hloA + (size_t)B * H;
  f16*   hloB  = hhiB + (size_t)B * H;
  float* tblD  = (float*)(hloB + (size_t)B * H);     // 3*FH f32
  float* tblR  = tblD + 3 * FH;
  float* tblK  = tblR + 3 * FH;
  float* condp = tblK + 3 * FH;                      // 5*FH
  float* base0 = condp + 5 * FH;                     // FH
  int*   sel   = (int*)(base0 + FH);                 // B

  convertW_kernel<<<(FH * H / 4) / 256, 256, 0, stream>>>(W_hh, W16hi, W16lo);
  precompute_kernel<<<FH / 4, 256, 0, stream>>>(
      W_ih, b_ih, b_hh, depth_emb, ratio_emb, ks_emb, cond_emb, sc_emb, sid,
      tblD, tblR, tblK, condp, base0);
  step0_kernel<<<(B * H) / 256, 256, 0, stream>>>(constraints, condp, base0, hhiA, hloA, cb);

  const float* selW_arr[3] = {depth_W, width_W, ks_W};
  const float* selb_arr[3] = {depth_b, width_b, ks_b};
  const float vals[3][3]   = {{2.f,3.f,4.f},{3.f,4.f,6.f},{3.f,5.f,7.f}};
  float* tbl_arr[3]        = {tblD, tblR, tblK};

  const size_t DEPTHS = 0,            RATIOS = (size_t)5*B,   KSS    = (size_t)25*B,
               DWBS   = (size_t)45*B, DPROBS = (size_t)60*B,
               RWBS   = (size_t)75*B, RPROBS = (size_t)135*B,
               KWBS   = (size_t)195*B, KPROBS = (size_t)255*B;

  f16* hhi_cur = hhiA; f16* hlo_cur = hloA;
  f16* hhi_nxt = hhiB; f16* hlo_nxt = hloB;
  for (int t = 0; t < NSTEPS; ++t) {
    if (t > 0) {
      int pt = (t - 1) % 9;
      int ptype = (pt == 0) ? 0 : ((pt & 1) ? 1 : 2);
      lstm_step_mfma<<<512, 512, 0, stream>>>(
          hhi_cur, hlo_cur, hhi_nxt, hlo_nxt, cb, W16hi, W16lo, tbl_arr[ptype], sel);
      f16* th = hhi_cur; hhi_cur = hhi_nxt; hhi_nxt = th;
      f16* tl = hlo_cur; hlo_cur = hlo_nxt; hlo_nxt = tl;
    }
    int r = t % 9, u = t / 9;
    int ty, row;
    float *valp, *wbp, *pp;
    if (r == 0)      { ty = 0; row = u;
      valp = out + DEPTHS + (size_t)row*B; wbp = out + DWBS + (size_t)row*B*3; pp = out + DPROBS + (size_t)row*B*3; }
    else if (r & 1)  { ty = 1; row = u*4 + (r-1)/2;
      valp = out + RATIOS + (size_t)row*B; wbp = out + RWBS + (size_t)row*B*3; pp = out + RPROBS + (size_t)row*B*3; }
    else             { ty = 2; row = u*4 + (r-2)/2;
      valp = out + KSS + (size_t)row*B;    wbp = out + KWBS + (size_t)row*B*3; pp = out + KPROBS + (size_t)row*B*3; }
    sampler_kernel<<<B / 4, 256, 0, stream>>>(
        hhi_cur, hlo_cur, selW_arr[ty], selb_arr[ty], gumbel + (size_t)t * B * 3,
        valp, wbp, pp, vals[ty][0], vals[ty][1], vals[ty][2], sel);
  }
}

// Round 11
// 5381.965 us; speedup vs baseline: 1.0234x; 1.0234x over previous
//
#include <hip/hip_runtime.h>
#include <cmath>

namespace {

typedef _Float16 f16;
typedef f16 f16x8 __attribute__((ext_vector_type(8)));
typedef f16 f16x4 __attribute__((ext_vector_type(4)));
typedef float f32x4 __attribute__((ext_vector_type(4)));

constexpr int B  = 4096;
constexpr int H  = 1024;
constexpr int FH = 4 * H;   // 4096
constexpr int NSTEPS = 45;
constexpr float INVS = 1.0f / 2048.0f;

__device__ __forceinline__ float sigf(float x) { return 1.0f / (1.0f + expf(-x)); }

struct HL { f16 h, l; };
// safe split: hi is 0 or a normal f16; lo = f16((a-hi)*2048) (normal or negligible)
__device__ __forceinline__ HL split16(float a) {
  float ah = (float)(f16)a;
  if (fabsf(a) < 6.1035156e-5f) ah = 0.0f;   // would-be-subnormal hi -> push all into lo
  HL r; r.h = (f16)ah; r.l = (f16)((a - ah) * 2048.0f); return r;
}

// h fragment-pack layout: unit u = (b>>4)*32 + (j>>5)  (16 b-rows x 32 j per unit)
//   elem off = ((b&15) + 16*((j>>3)&3))*8 + (j&7);  hi at u*1024+off, lo at +512.
// This is exactly the mfma_f32_16x16x32 A-operand order: lane l reads
// hi frag = pack + u*1024 + l*8 (row l&15, k-chunk (l>>4)*8).

// ---------------- one-time: pack W_hh (hi/lo split) into MFMA-fragment order ------
// packed elem addr = jb*262144 + kt*8192 + wn*4096 + nf*1024 + hl*512 + lane*8
// content: W_hl[row = nf*1024 + jb*32 + wn*16 + (lane&15)][k = kt*32 + (lane>>4)*8 + 0..7]
__global__ void packW_kernel(const float* __restrict__ W, f16* __restrict__ packed) {
  int tid  = blockIdx.x * 256 + threadIdx.x;      // 0 .. 1048575
  int lane = tid & 63;
  int rest = tid >> 6;
  int hl = rest & 1;
  int nf = (rest >> 1) & 3;
  int wn = (rest >> 3) & 1;
  int kt = (rest >> 4) & 31;
  int jb = rest >> 9;
  int row = nf * 1024 + jb * 32 + wn * 16 + (lane & 15);
  int kk  = kt * 32 + (lane >> 4) * 8;
  const float* src = W + (size_t)row * H + kk;
  f16x8 v;
  #pragma unroll
  for (int i = 0; i < 8; ++i) {
    HL s = split16(src[i]);
    v[i] = hl ? s.l : s.h;
  }
  *(f16x8*)(packed + (size_t)tid * 8) = v;
}

// ---------------- one-time precompute of x-path tables (wave-parallel) ----------------
__global__ void precompute_kernel(
    const float* __restrict__ W_ih, const float* __restrict__ b_ih, const float* __restrict__ b_hh,
    const float* __restrict__ depth_emb, const float* __restrict__ ratio_emb, const float* __restrict__ ks_emb,
    const float* __restrict__ cond_emb, const float* __restrict__ sc_emb, const int* __restrict__ sid_p,
    float* __restrict__ tblD, float* __restrict__ tblR, float* __restrict__ tblK,
    float* __restrict__ condp, float* __restrict__ base0) {
  const int w4   = threadIdx.x >> 6;
  const int lane = threadIdx.x & 63;
  const int j    = blockIdx.x * 4 + w4;
  const float* wr = W_ih + (size_t)j * H;
  const int k = lane * 16;
  float4 wv0 = *(const float4*)(wr + k);
  float4 wv1 = *(const float4*)(wr + k + 4);
  float4 wv2 = *(const float4*)(wr + k + 8);
  float4 wv3 = *(const float4*)(wr + k + 12);

  auto dot = [&](const float* e) -> float {
    float4 e0 = *(const float4*)(e);
    float4 e1 = *(const float4*)(e + 4);
    float4 e2 = *(const float4*)(e + 8);
    float4 e3 = *(const float4*)(e + 12);
    return e0.x*wv0.x + e0.y*wv0.y + e0.z*wv0.z + e0.w*wv0.w
         + e1.x*wv1.x + e1.y*wv1.y + e1.z*wv1.z + e1.w*wv1.w
         + e2.x*wv2.x + e2.y*wv2.y + e2.z*wv2.z + e2.w*wv2.w
         + e3.x*wv3.x + e3.y*wv3.y + e3.z*wv3.z + e3.w*wv3.w;
  };

  float a[15];
  a[0] = dot(depth_emb + k);       a[1] = dot(depth_emb + H + k);   a[2] = dot(depth_emb + 2*H + k);
  a[3] = dot(ratio_emb + k);       a[4] = dot(ratio_emb + H + k);   a[5] = dot(ratio_emb + 2*H + k);
  a[6] = dot(ks_emb + k);          a[7] = dot(ks_emb + H + k);      a[8] = dot(ks_emb + 2*H + k);
  a[9] = a[10] = a[11] = a[12] = a[13] = a[14] = 0.0f;
  constexpr int HH = H / 2;
  int sid = sid_p[0];
  if (lane < 32) {
    a[9]  = dot(cond_emb + 0*HH + k);
    a[10] = dot(cond_emb + 1*HH + k);
    a[11] = dot(cond_emb + 2*HH + k);
    a[12] = dot(cond_emb + 3*HH + k);
    a[13] = dot(cond_emb + 4*HH + k);
  } else {
    a[14] = dot(sc_emb + sid*HH + (k - HH));   // pairs with wr[HH + kk]
  }
  #pragma unroll
  for (int i = 0; i < 15; ++i) {
    #pragma unroll
    for (int off = 32; off > 0; off >>= 1) a[i] += __shfl_xor(a[i], off);
  }
  if (lane == 0) {
    float bias = b_ih[j] + b_hh[j];
    tblD[0*FH+j]=a[0]+bias; tblD[1*FH+j]=a[1]+bias; tblD[2*FH+j]=a[2]+bias;
    tblR[0*FH+j]=a[3]+bias; tblR[1*FH+j]=a[4]+bias; tblR[2*FH+j]=a[5]+bias;
    tblK[0*FH+j]=a[6]+bias; tblK[1*FH+j]=a[7]+bias; tblK[2*FH+j]=a[8]+bias;
    condp[0*FH+j]=a[9]; condp[1*FH+j]=a[10]; condp[2*FH+j]=a[11];
    condp[3*FH+j]=a[12]; condp[4*FH+j]=a[13];
    base0[j] = a[14] + bias;
  }
}

// ---------------- step 0: h=c=0; writes h in fragment-pack layout ----------------
__global__ void step0_kernel(const float* __restrict__ constraints,
                             const float* __restrict__ condp, const float* __restrict__ base0,
                             f16* __restrict__ hpack, float* __restrict__ c) {
  int idx = blockIdx.x * blockDim.x + threadIdx.x;   // b*H + j
  int b = idx >> 10;
  int j = idx & (H - 1);
  float cv = constraints[b];
  int i0 = 0;
  if (cv >= 12.5f) i0 = 1;
  if (cv >= 15.0f) i0 = 2;
  if (cv >= 17.5f) i0 = 3;
  float right = 10.0f + 2.5f * (float)(i0 + 1);
  float w = (right - cv) / 2.5f;
  const float* c0 = condp + (size_t)i0 * FH;
  const float* c1 = c0 + FH;
  float iw = 1.0f - w;
  float xi = w*c0[j]       + iw*c1[j]       + base0[j];
  float xg = w*c0[2*H+j]   + iw*c1[2*H+j]   + base0[2*H+j];
  float xo = w*c0[3*H+j]   + iw*c1[3*H+j]   + base0[3*H+j];
  float cn = sigf(xi) * tanhf(xg);
  float hn = sigf(xo) * tanhf(cn);
  c[idx] = cn;
  HL s = split16(hn);
  size_t u = (size_t)((b >> 4) * 32 + (j >> 5));
  int off = ((b & 15) + 16 * ((j >> 3) & 3)) * 8 + (j & 7);
  hpack[u * 1024 + off]       = s.h;
  hpack[u * 1024 + off + 512] = s.l;
}

// ---------------- MFMA LSTM step: 256x128 tile, 8 waves, NO LDS / NO barriers ------
// A (h) and B (W) both stream fragment-packed global(L2) -> registers.
// B double-buffered (full-tile prefetch); A issued first each iter (oldest
// outstanding -> near-free vmcnt); waves fully unsynchronized.
__global__ __launch_bounds__(512, 1) void lstm_step_mfma(
    const f16* __restrict__ hpack, f16* __restrict__ npack,
    float* __restrict__ cbuf,
    const f16* __restrict__ packW,
    const float* __restrict__ tbl, const int* __restrict__ sel) {
  const int tid  = threadIdx.x;
  const int lane = tid & 63;
  const int w    = tid >> 6;
  const int wm   = w >> 1, wn = w & 1;
  const int l15  = lane & 15;
  const int kq   = lane >> 4;

  // XCD-clustered tile assignment (per-XCD W slice stays in its private L2)
  const int L   = blockIdx.x;          // 0..511
  const int xcd = L & 7, seq = L >> 3;
  const int jb  = (xcd << 2) + (seq & 3);
  const int bb  = seq >> 2;
  const int b0  = bb << 8;
  const int j0  = jb << 5;

  f32x4 accH[4][4] = {};
  f32x4 accL[4][4] = {};

  // A fragment bases: unit (bblk*32 + kt), bblk = b0/16 + wm*4 + mf
  const f16* abase[4];
  #pragma unroll
  for (int mf = 0; mf < 4; ++mf)
    abase[mf] = hpack + ((size_t)((b0 >> 4) + wm * 4 + mf) * 32) * 1024 + lane * 8;

  // B fragment base (R7-verified packW layout)
  const f16* wb = packW + (size_t)jb * 262144 + wn * 4096 + lane * 8;

  f16x8 bhX[4], blX[4], bhY[4], blY[4];

  // preload B(0)
  #pragma unroll
  for (int nf = 0; nf < 4; ++nf) {
    bhX[nf] = *(const f16x8*)(wb + nf * 1024);
    blX[nf] = *(const f16x8*)(wb + nf * 1024 + 512);
  }

  auto tile = [&](int kt, f16x8 (&bhC)[4], f16x8 (&blC)[4],
                          f16x8 (&bhN)[4], f16x8 (&blN)[4]) {
    // A loads first (oldest outstanding -> compiler wait is near-free)
    f16x8 ah[4], al[4];
    #pragma unroll
    for (int mf = 0; mf < 4; ++mf) ah[mf] = *(const f16x8*)(abase[mf] + kt * 1024);
    #pragma unroll
    for (int mf = 0; mf < 4; ++mf) al[mf] = *(const f16x8*)(abase[mf] + kt * 1024 + 512);
    // B prefetch for kt+1 (consumed next iteration -> full-tile distance)
    if (kt < 31) {
      const f16* wt = wb + (size_t)(kt + 1) * 8192;
      #pragma unroll
      for (int nf = 0; nf < 4; ++nf) {
        bhN[nf] = *(const f16x8*)(wt + nf * 1024);
        blN[nf] = *(const f16x8*)(wt + nf * 1024 + 512);
      }
    }
    #pragma unroll
    for (int mf = 0; mf < 4; ++mf)
      #pragma unroll
      for (int nf = 0; nf < 4; ++nf)
        accH[mf][nf] = __builtin_amdgcn_mfma_f32_16x16x32_f16(ah[mf], bhC[nf], accH[mf][nf], 0, 0, 0);
    #pragma unroll
    for (int mf = 0; mf < 4; ++mf)
      #pragma unroll
      for (int nf = 0; nf < 4; ++nf)
        accL[mf][nf] = __builtin_amdgcn_mfma_f32_16x16x32_f16(ah[mf], blC[nf], accL[mf][nf], 0, 0, 0);
    #pragma unroll
    for (int mf = 0; mf < 4; ++mf)
      #pragma unroll
      for (int nf = 0; nf < 4; ++nf)
        accL[mf][nf] = __builtin_amdgcn_mfma_f32_16x16x32_f16(al[mf], bhC[nf], accL[mf][nf], 0, 0, 0);
  };

  for (int kt = 0; kt < 32; kt += 2) {
    tile(kt,     bhX, blX, bhY, blY);
    tile(kt + 1, bhY, blY, bhX, blX);
  }

  // epilogue: gates -> LSTM cell -> c (plain), h (fragment-packed hi/lo)
  const int j = j0 + wn * 16 + l15;
  const int eoff = (wn * 2 + (l15 >> 3)) * 128 + (l15 & 7);   // j-part of pack elem off
  #pragma unroll
  for (int mf = 0; mf < 4; ++mf) {
    const size_t ubase = ((size_t)((b0 >> 4) + wm * 4 + mf) * 32 + jb) * 1024;
    #pragma unroll
    for (int r = 0; r < 4; ++r) {
      int b = b0 + wm * 64 + mf * 16 + kq * 4 + r;
      int s = sel[b];
      const float* tb = tbl + (size_t)s * FH + j;
      float gi = accH[mf][0][r] + accL[mf][0][r] * INVS + tb[0];
      float gf = accH[mf][1][r] + accL[mf][1][r] * INVS + tb[H];
      float gg = accH[mf][2][r] + accL[mf][2][r] * INVS + tb[2*H];
      float go = accH[mf][3][r] + accL[mf][3][r] * INVS + tb[3*H];
      size_t off = (size_t)b * H + j;
      float cp = cbuf[off];
      float cn = sigf(gf) * cp + sigf(gi) * tanhf(gg);
      float hn = sigf(go) * tanhf(cn);
      cbuf[off] = cn;
      HL sp = split16(hn);
      size_t pa = ubase + (size_t)((kq * 4 + r) * 8 + eoff);
      npack[pa]       = sp.h;
      npack[pa + 512] = sp.l;
    }
  }
}

// ---------------- sampler (reads fragment-packed h) ----------------
__global__ void sampler_kernel(const f16* __restrict__ hpack,
                               const float* __restrict__ selW, const float* __restrict__ selb,
                               const float* __restrict__ gu,
                               float* __restrict__ val_out, float* __restrict__ wb_out,
                               float* __restrict__ p_out,
                               float v0, float v1, float v2,
                               int* __restrict__ sel) {
  int wave = threadIdx.x >> 6;
  int lane = threadIdx.x & 63;
  int b = blockIdx.x * 4 + wave;
  const f16* hp = hpack + ((size_t)(b >> 4) * 32) * 1024 + (b & 15) * 8;
  float acc0 = 0, acc1 = 0, acc2 = 0;
  #pragma unroll
  for (int c2 = 0; c2 < 2; ++c2) {
    int c = lane + c2 * 64;                       // j-chunk 0..127 (8 j each)
    const f16* base = hp + (c >> 2) * 1024 + (c & 3) * 128;
    f16x8 vh = *(const f16x8*)(base);
    f16x8 vl = *(const f16x8*)(base + 512);
    int j = c * 8;
    const float* w0p = selW + j;
    const float* w1p = selW + H + j;
    const float* w2p = selW + 2 * H + j;
    #pragma unroll
    for (int i = 0; i < 8; ++i) {
      float x = (float)vh[i] + (float)vl[i] * INVS;
      acc0 += x * w0p[i];
      acc1 += x * w1p[i];
      acc2 += x * w2p[i];
    }
  }
  #pragma unroll
  for (int off = 32; off > 0; off >>= 1) {
    acc0 += __shfl_xor(acc0, off);
    acc1 += __shfl_xor(acc1, off);
    acc2 += __shfl_xor(acc2, off);
  }
  if (lane == 0) {
    float y0 = acc0 + selb[0] - logf(-logf(gu[(size_t)b*3 + 0]));
    float y1 = acc1 + selb[1] - logf(-logf(gu[(size_t)b*3 + 1]));
    float y2 = acc2 + selb[2] - logf(-logf(gu[(size_t)b*3 + 2]));
    int s = 0;
    float best = y0;
    if (y1 > best) { s = 1; best = y1; }
    if (y2 > best) { s = 2; best = y2; }
    float e0 = expf(y0 - best), e1 = expf(y1 - best), e2 = expf(y2 - best);
    float inv = 1.0f / (e0 + e1 + e2);
    float p0 = e0 * inv, p1 = e1 * inv, p2 = e2 * inv;
    val_out[b] = (s == 0) ? v0 : ((s == 1) ? v1 : v2);
    wb_out[(size_t)b*3 + 0] = (s == 0) ? 1.0f : 0.0f;
    wb_out[(size_t)b*3 + 1] = (s == 1) ? 1.0f : 0.0f;
    wb_out[(size_t)b*3 + 2] = (s == 2) ? 1.0f : 0.0f;
    p_out[(size_t)b*3 + 0] = p0;
    p_out[(size_t)b*3 + 1] = p1;
    p_out[(size_t)b*3 + 2] = p2;
    sel[b] = s;
  }
}

}  // namespace

extern "C" void kernel_launch(void* const* d_in, const int* in_sizes, int n_in,
                              void* d_out, int out_size, void* d_ws, size_t ws_size,
                              hipStream_t stream) {
  (void)in_sizes; (void)n_in; (void)out_size; (void)ws_size;
  const float* constraints = (const float*)d_in[0];
  const int*   sid         = (const int*)d_in[1];
  const float* gumbel      = (const float*)d_in[2];
  const float* cond_emb    = (const float*)d_in[3];
  const float* sc_emb      = (const float*)d_in[4];
  const float* depth_emb   = (const float*)d_in[5];
  const float* ratio_emb   = (const float*)d_in[6];
  const float* ks_emb      = (const float*)d_in[7];
  const float* W_ih        = (const float*)d_in[8];
  const float* b_ih        = (const float*)d_in[9];
  const float* W_hh        = (const float*)d_in[10];
  const float* b_hh        = (const float*)d_in[11];
  const float* depth_W     = (const float*)d_in[12];
  const float* depth_b     = (const float*)d_in[13];
  const float* width_W     = (const float*)d_in[14];
  const float* width_b     = (const float*)d_in[15];
  const float* ks_W        = (const float*)d_in[16];
  const float* ks_b        = (const float*)d_in[17];

  float* out = (float*)d_out;
  float* ws  = (float*)d_ws;

  float* cb    = ws;                                 // B*H f32 (16MB)
  f16*   packW = (f16*)(cb + (size_t)B * H);         // 8M f16 (16MB), fragment-packed W
  f16*   hpkA  = packW + (size_t)8 * 1024 * 1024;    // B*H*2 f16 (16MB), packed h hi/lo
  f16*   hpkB  = hpkA + (size_t)B * H * 2;           // 16MB
  float* tblD  = (float*)(hpkB + (size_t)B * H * 2); // 3*FH f32
  float* tblR  = tblD + 3 * FH;
  float* tblK  = tblR + 3 * FH;
  float* condp = tblK + 3 * FH;                      // 5*FH
  float* base0 = condp + 5 * FH;                     // FH
  int*   sel   = (int*)(base0 + FH);                 // B

  packW_kernel<<<4096, 256, 0, stream>>>(W_hh, packW);
  precompute_kernel<<<FH / 4, 256, 0, stream>>>(
      W_ih, b_ih, b_hh, depth_emb, ratio_emb, ks_emb, cond_emb, sc_emb, sid,
      tblD, tblR, tblK, condp, base0);
  step0_kernel<<<(B * H) / 256, 256, 0, stream>>>(constraints, condp, base0, hpkA, cb);

  const float* selW_arr[3] = {depth_W, width_W, ks_W};
  const float* selb_arr[3] = {depth_b, width_b, ks_b};
  const float vals[3][3]   = {{2.f,3.f,4.f},{3.f,4.f,6.f},{3.f,5.f,7.f}};
  float* tbl_arr[3]        = {tblD, tblR, tblK};

  const size_t DEPTHS = 0,            RATIOS = (size_t)5*B,   KSS    = (size_t)25*B,
               DWBS   = (size_t)45*B, DPROBS = (size_t)60*B,
               RWBS   = (size_t)75*B, RPROBS = (size_t)135*B,
               KWBS   = (size_t)195*B, KPROBS = (size_t)255*B;

  f16* hcur = hpkA;
  f16* hnxt = hpkB;
  for (int t = 0; t < NSTEPS; ++t) {
    if (t > 0) {
      int pt = (t - 1) % 9;
      int ptype = (pt == 0) ? 0 : ((pt & 1) ? 1 : 2);
      lstm_step_mfma<<<512, 512, 0, stream>>>(
          hcur, hnxt, cb, packW, tbl_arr[ptype], sel);
      f16* tmp = hcur; hcur = hnxt; hnxt = tmp;
    }
    int r = t % 9, u = t / 9;
    int ty, row;
    float *valp, *wbp, *pp;
    if (r == 0)      { ty = 0; row = u;
      valp = out + DEPTHS + (size_t)row*B; wbp = out + DWBS + (size_t)row*B*3; pp = out + DPROBS + (size_t)row*B*3; }
    else if (r & 1)  { ty = 1; row = u*4 + (r-1)/2;
      valp = out + RATIOS + (size_t)row*B; wbp = out + RWBS + (size_t)row*B*3; pp = out + RPROBS + (size_t)row*B*3; }
    else             { ty = 2; row = u*4 + (r-2)/2;
      valp = out + KSS + (size_t)row*B;    wbp = out + KWBS + (size_t)row*B*3; pp = out + KPROBS + (size_t)row*B*3; }
    sampler_kernel<<<B / 4, 256, 0, stream>>>(
        hcur, selW_arr[ty], selb_arr[ty], gumbel + (size_t)t * B * 3,
        valp, wbp, pp, vals[ty][0], vals[ty][1], vals[ty][2], sel);
  }
}